// Round 1
// baseline (539.066 us; speedup 1.0000x reference)
//
#include <hip/hip_runtime.h>
#include <math.h>

#define BN_ 16
#define SS  2048
#define HH  1024
#define AA  64
#define INV_SCALE 0.125f   // 1/sqrt(64)

// ---------------- ws layout (float offsets) ----------------
#define QK_OFF   0
#define QK_SZ    (BN_*SS*128)          // Q in cols 0..63, K in cols 64..127
#define WT_OFF   (QK_OFF + QK_SZ)      // W^T staging [128][1024]
#define WT_SZ    (128*HH)
#define L_OFF    (WT_OFF + WT_SZ)      // softmax denominators [BN_*SS]
#define CA_OFF   (L_OFF + BN_*SS)      // colsum over all rows [BN_*SS]
#define CM_OFF   (CA_OFF + BN_*SS)     // colsum over qmask rows [BN_*SS]
#define W_OFF    (CM_OFF + BN_*SS)     // w[b][t]
#define NB_OFF   (W_OFF + BN_*SS)      // Nb per batch [16]
#define WSUM_OFF (NB_OFF + 16)         // sum of w per batch [16]
#define U_OFF    (WSUM_OFF + 16)       // u[b][c] [BN_*HH]

// swizzled LDS index for a [row][64] tile (keeps b128 reads ~conflict-free)
__device__ __forceinline__ int swz(int row, int a) {
    return row * 64 + (a ^ (((row >> 3) & 7) << 2));
}

// load a 128-row x 64-col fp32 tile (global row stride = stride floats) into swizzled LDS
__device__ __forceinline__ void load_tile(float* dst, const float* __restrict__ src,
                                          int stride, int tid) {
    int c  = tid & 15;      // float4 column
    int r0 = tid >> 4;      // 16 rows per pass
    #pragma unroll
    for (int pass = 0; pass < 8; ++pass) {
        int r = r0 + pass * 16;
        float4 v = *(const float4*)&src[(size_t)r * stride + 4 * c];
        *(float4*)&dst[swz(r, 4 * c)] = v;
    }
}

// acc[8][8] += A[8p+i][:64] . B[8q+j][:64]   (both tiles swizzled)
__device__ __forceinline__ void tile_gemm(const float* As, const float* Bs,
                                          int p, int q, float acc[8][8]) {
    #pragma unroll 2
    for (int ac = 0; ac < 64; ac += 4) {
        float4 av[8], bw[8];
        #pragma unroll
        for (int i = 0; i < 8; ++i) av[i] = *(const float4*)&As[swz(8 * p + i, ac)];
        #pragma unroll
        for (int j = 0; j < 8; ++j) bw[j] = *(const float4*)&Bs[swz(8 * q + j, ac)];
        #pragma unroll
        for (int i = 0; i < 8; ++i)
            #pragma unroll
            for (int j = 0; j < 8; ++j)
                acc[i][j] += av[i].x * bw[j].x + av[i].y * bw[j].y
                           + av[i].z * bw[j].z + av[i].w * bw[j].w;
    }
}

// ---- A: transpose Wq||Wk -> wt[128][1024] ----
__global__ __launch_bounds__(256) void k_wt(const float* __restrict__ Wq,
                                            const float* __restrict__ Wk,
                                            float* __restrict__ wt) {
    int n = blockIdx.x;
    const float* src = (n < 64) ? &Wq[n] : &Wk[n - 64];
    for (int k = threadIdx.x; k < HH; k += 256)
        wt[(size_t)n * HH + k] = src[(size_t)k * AA];
}

// ---- B: QK projection GEMM: qk[m][n] = x[m][:] . wt[n][:] + bias ----
__global__ __launch_bounds__(256, 1) void k_qkproj(const float* __restrict__ x,
                                                   const float* __restrict__ wt,
                                                   const float* __restrict__ bq,
                                                   const float* __restrict__ bk,
                                                   float* __restrict__ qk) {
    __shared__ __align__(16) float xs[8192];
    __shared__ __align__(16) float ws2[8192];
    int tid = threadIdx.x;
    int m0 = blockIdx.x * 128;
    int p = tid & 15, q = tid >> 4;
    float acc[8][8] = {};
    for (int kt = 0; kt < 16; ++kt) {
        __syncthreads();
        load_tile(xs,  &x[(size_t)m0 * HH + kt * 64], HH, tid);
        load_tile(ws2, &wt[kt * 64],                  HH, tid);
        __syncthreads();
        tile_gemm(xs, ws2, p, q, acc);
    }
    #pragma unroll
    for (int i = 0; i < 8; ++i) {
        int gm = m0 + 8 * p + i;
        #pragma unroll
        for (int j = 0; j < 8; ++j) {
            int n = 8 * q + j;
            float bias = (n < 64) ? bq[n] : bk[n - 64];
            qk[(size_t)gm * 128 + n] = acc[i][j] + bias;
        }
    }
}

// ---- E: Nb per batch ----
__global__ __launch_bounds__(256) void k_nb(const int* __restrict__ mask,
                                            float* __restrict__ nbv) {
    int b = blockIdx.x, tid = threadIdx.x;
    int s = 0;
    for (int i = tid; i < SS; i += 256) s += mask[b * SS + i];
    float fs = (float)s;
    for (int off = 1; off < 64; off <<= 1) fs += __shfl_xor(fs, off);
    __shared__ float red[4];
    if ((tid & 63) == 0) red[tid >> 6] = fs;
    __syncthreads();
    if (tid == 0) nbv[b] = red[0] + red[1] + red[2] + red[3] + 1e-8f;
}

// ---- C: softmax denominators l[b][s] (t-split via atomics) ----
__global__ __launch_bounds__(256, 2) void k_rowsum(const float* __restrict__ qk,
                                                   const int* __restrict__ mask,
                                                   float* __restrict__ l) {
    int b = blockIdx.x, sblk = blockIdx.y, th = blockIdx.z;
    __shared__ __align__(16) float Qs[8192];
    __shared__ __align__(16) float Ks[8192];
    __shared__ float pmsh[1024];
    __shared__ float rowacc[128];
    int tid = threadIdx.x;
    for (int i = tid; i < 1024; i += 256)
        pmsh[i] = mask[b * SS + th * 1024 + i] ? 1.f : 0.f;
    if (tid < 128) rowacc[tid] = 0.f;
    int s0 = sblk * 128;
    load_tile(Qs, &qk[(size_t)(b * SS + s0) * 128], 128, tid);
    int p = tid & 15, q = tid >> 4;
    float rsum[8] = {};
    for (int tt = 0; tt < 8; ++tt) {
        __syncthreads();
        load_tile(Ks, &qk[(size_t)(b * SS + th * 1024 + tt * 128) * 128 + 64], 128, tid);
        __syncthreads();
        float acc[8][8] = {};
        tile_gemm(Qs, Ks, p, q, acc);
        #pragma unroll
        for (int j = 0; j < 8; ++j) {
            float pm = pmsh[tt * 128 + 8 * q + j];
            #pragma unroll
            for (int i = 0; i < 8; ++i)
                rsum[i] += pm * __expf(acc[i][j] * INV_SCALE);
        }
    }
    __syncthreads();
    #pragma unroll
    for (int i = 0; i < 8; ++i) atomicAdd(&rowacc[8 * p + i], rsum[i]);
    __syncthreads();
    if (tid < 128) atomicAdd(&l[b * SS + s0 + tid], rowacc[tid]);
}

// ---- D: column sums of attn (all rows and qmasked rows) ----
__global__ __launch_bounds__(256, 2) void k_colsum(const float* __restrict__ qk,
                                                   const int* __restrict__ mask,
                                                   const float* __restrict__ l,
                                                   float* __restrict__ ca,
                                                   float* __restrict__ cm) {
    int b = blockIdx.x, sblk = blockIdx.y, th = blockIdx.z;
    __shared__ __align__(16) float Qs[8192];
    __shared__ __align__(16) float Ks[8192];
    __shared__ float pmsh[1024];
    int tid = threadIdx.x;
    for (int i = tid; i < 1024; i += 256)
        pmsh[i] = mask[b * SS + th * 1024 + i] ? 1.f : 0.f;
    int s0 = sblk * 128;
    load_tile(Qs, &qk[(size_t)(b * SS + s0) * 128], 128, tid);
    int p = tid & 15, q = tid >> 4;
    float inv_l[8], qm[8];
    #pragma unroll
    for (int i = 0; i < 8; ++i) {
        int s = s0 + 8 * p + i;
        float lv = l[b * SS + s];
        inv_l[i] = (lv > 0.f) ? 1.f / lv : 0.f;
        qm[i] = mask[b * SS + s] ? 1.f : 0.f;
    }
    for (int tt = 0; tt < 8; ++tt) {
        __syncthreads();
        load_tile(Ks, &qk[(size_t)(b * SS + th * 1024 + tt * 128) * 128 + 64], 128, tid);
        __syncthreads();
        float acc[8][8] = {};
        tile_gemm(Qs, Ks, p, q, acc);
        float cal[8] = {}, cml[8] = {};
        #pragma unroll
        for (int j = 0; j < 8; ++j) {
            float pm = pmsh[tt * 128 + 8 * q + j];
            #pragma unroll
            for (int i = 0; i < 8; ++i) {
                float pv = pm * __expf(acc[i][j] * INV_SCALE) * inv_l[i];
                cal[j] += pv;
                cml[j] += qm[i] * pv;
            }
        }
        // reduce over p (low 4 lane bits)
        #pragma unroll
        for (int off = 1; off < 16; off <<= 1) {
            #pragma unroll
            for (int j = 0; j < 8; ++j) {
                cal[j] += __shfl_xor(cal[j], off);
                cml[j] += __shfl_xor(cml[j], off);
            }
        }
        if (p == 0) {
            int tg = b * SS + th * 1024 + tt * 128 + 8 * q;
            #pragma unroll
            for (int j = 0; j < 8; ++j) {
                atomicAdd(&ca[tg + j], cal[j]);
                atomicAdd(&cm[tg + j], cml[j]);
            }
        }
    }
}

// ---- F: w, attn_mean, wsum ----
__global__ __launch_bounds__(256) void k_finalize(const float* __restrict__ ca,
                                                  const float* __restrict__ cmv,
                                                  const float* __restrict__ nbv,
                                                  float* __restrict__ w,
                                                  float* __restrict__ wsum,
                                                  float* __restrict__ out_mean) {
    int b = blockIdx.x;
    int t = blockIdx.y * 256 + threadIdx.x;
    float cav = ca[b * SS + t];
    out_mean[b * SS + t] = cav * (1.f / SS);
    float wv = cmv[b * SS + t] / nbv[b];
    w[b * SS + t] = wv;
    float s = wv;
    for (int off = 1; off < 64; off <<= 1) s += __shfl_xor(s, off);
    if ((threadIdx.x & 63) == 0) atomicAdd(&wsum[b], s);
}

// ---- G: u[b][c] = sum_t w[b][t] * x[b][t][c] ----
__global__ __launch_bounds__(256) void k_u(const float* __restrict__ x,
                                           const float* __restrict__ w,
                                           float* __restrict__ u) {
    int b = blockIdx.x;
    int c = blockIdx.y * 256 + threadIdx.x;
    int t0 = blockIdx.z * 256;
    const float* xb = &x[((size_t)b * SS + t0) * HH + c];
    const float* wb = &w[b * SS + t0];
    float acc = 0.f;
    #pragma unroll 8
    for (int t = 0; t < 256; ++t)
        acc += wb[t] * xb[(size_t)t * HH];
    atomicAdd(&u[b * HH + c], acc);
}

// ---- H: out0[b][h] = sum_c u[b][c]*Wv[c][h] + bv[h]*wsum[b] ----
__global__ __launch_bounds__(256) void k_out0(const float* __restrict__ u,
                                              const float* __restrict__ Wv,
                                              const float* __restrict__ bv,
                                              const float* __restrict__ wsum,
                                              float* __restrict__ out) {
    int b = blockIdx.x;
    int h = blockIdx.y * 256 + threadIdx.x;
    const float* ub = &u[b * HH];
    float acc = bv[h] * wsum[b];
    #pragma unroll 8
    for (int c = 0; c < HH; ++c)
        acc += ub[c] * Wv[(size_t)c * HH + h];
    out[b * HH + h] = acc;
}

extern "C" void kernel_launch(void* const* d_in, const int* in_sizes, int n_in,
                              void* d_out, int out_size, void* d_ws, size_t ws_size,
                              hipStream_t stream) {
    const float* x  = (const float*)d_in[0];
    const int* mask = (const int*)d_in[1];
    const float* Wq = (const float*)d_in[2];
    const float* bq = (const float*)d_in[3];
    const float* Wk = (const float*)d_in[4];
    const float* bk = (const float*)d_in[5];
    const float* Wv = (const float*)d_in[6];
    const float* bv = (const float*)d_in[7];
    float* out = (float*)d_out;
    float* ws  = (float*)d_ws;

    float* qk   = ws + QK_OFF;
    float* wt   = ws + WT_OFF;
    float* l    = ws + L_OFF;
    float* ca   = ws + CA_OFF;
    float* cm   = ws + CM_OFF;
    float* w    = ws + W_OFF;
    float* nbv  = ws + NB_OFF;
    float* wsum = ws + WSUM_OFF;
    float* u    = ws + U_OFF;

    // zero the accumulated buffers (l, ca, cm contiguous; wsum, u contiguous)
    hipMemsetAsync(l, 0, (size_t)3 * BN_ * SS * sizeof(float), stream);
    hipMemsetAsync(wsum, 0, (size_t)(16 + BN_ * HH) * sizeof(float), stream);

    k_wt    <<<dim3(128),        dim3(256), 0, stream>>>(Wq, Wk, wt);
    k_qkproj<<<dim3(256),        dim3(256), 0, stream>>>(x, wt, bq, bk, qk);
    k_nb    <<<dim3(BN_),        dim3(256), 0, stream>>>(mask, nbv);
    k_rowsum<<<dim3(BN_, 16, 2), dim3(256), 0, stream>>>(qk, mask, l);
    k_colsum<<<dim3(BN_, 16, 2), dim3(256), 0, stream>>>(qk, mask, l, ca, cm);
    k_finalize<<<dim3(BN_, 8),   dim3(256), 0, stream>>>(ca, cm, nbv, w, wsum, out + BN_ * HH);
    k_u     <<<dim3(BN_, 4, 8),  dim3(256), 0, stream>>>(x, w, u);
    k_out0  <<<dim3(BN_, 4),     dim3(256), 0, stream>>>(u, Wv, bv, wsum, out);
}

// Round 2
// 191.657 us; speedup vs baseline: 2.8127x; 2.8127x over previous
//
#include <hip/hip_runtime.h>
#include <math.h>

#define BN_ 16
#define SS  2048
#define HH  1024
#define AA  64

typedef unsigned short u16;
typedef __bf16 bf16x8 __attribute__((ext_vector_type(8)));
typedef float  f32x4  __attribute__((ext_vector_type(4)));
#define MFMA16 __builtin_amdgcn_mfma_f32_16x16x32_bf16

// ---------------- ws layout (float offsets) ----------------
#define QK_OFF   0
#define QK_FLOATS (BN_*SS*64)          // bf16 qk[32768][128]: Q cols 0..63, K cols 64..127
#define WT_OFF   (QK_OFF + QK_FLOATS)  // bf16 wt[128][1024] (WqT||WkT)
#define WT_FLOATS (64*HH)
#define L_OFF    (WT_OFF + WT_FLOATS)  // softmax denominators [BN_*SS]
#define CA_OFF   (L_OFF + BN_*SS)      // colsum all rows [BN_*SS]
#define CM_OFF   (CA_OFF + BN_*SS)     // colsum qmask rows [BN_*SS]
#define W_OFF    (CM_OFF + BN_*SS)     // w[b][t]
#define NB_OFF   (W_OFF + BN_*SS)      // Nb per batch [16]
#define WSUM_OFF (NB_OFF + 16)         // sum of w per batch [16]
#define U_OFF    (WSUM_OFF + 16)       // u[b][c] [BN_*HH]

__device__ __forceinline__ u16 f2b(float f) {
    unsigned u = __builtin_bit_cast(unsigned, f);
    return (u16)((u + 0x7FFFu + ((u >> 16) & 1u)) >> 16);
}

// swizzled elem index in a [128][64] bf16 LDS tile (row stride 128B)
__device__ __forceinline__ int swze(int row, int e) {
    return row * 64 + (e ^ ((row & 7) << 3));
}

// MFMA A/B fragment from swizzled tile: rows row16..row16+15, k-step ks (32 wide)
__device__ __forceinline__ bf16x8 ldfrag(const u16* t, int row16, int ks, int l6) {
    int row = row16 + (l6 & 15);
    int e = ks * 32 + ((l6 >> 4) << 3);
    return *(const bf16x8*)&t[swze(row, e)];
}

// stage a [128][64]-bf16 tile (16B chunks) from global (row stride gstride u16)
__device__ __forceinline__ void stage_bf16(u16* dst, const u16* __restrict__ src,
                                           int gstride, int tid) {
    int r = tid >> 3, c8 = tid & 7;
    #pragma unroll
    for (int pass = 0; pass < 4; ++pass) {
        int rr = r + pass * 32;
        uint4 v = *(const uint4*)&src[(size_t)rr * gstride + c8 * 8];
        *(uint4*)&dst[swze(rr, c8 * 8)] = v;
    }
}

// ---- A: transpose Wq||Wk -> bf16 wt[128][1024] ----
__global__ __launch_bounds__(256) void k_wt(const float* __restrict__ Wq,
                                            const float* __restrict__ Wk,
                                            u16* __restrict__ wt) {
    int n = blockIdx.x;
    const float* src = (n < 64) ? &Wq[n] : &Wk[n - 64];
    for (int k = threadIdx.x; k < HH; k += 256)
        wt[(size_t)n * HH + k] = f2b(src[(size_t)k * AA]);
}

// ---- B: QK projection via MFMA: qk[m][n] = x[m][:] . wt[n][:] + bias ----
__global__ __launch_bounds__(256) void k_qkproj(const float* __restrict__ x,
                                                const u16* __restrict__ wt,
                                                const float* __restrict__ bq,
                                                const float* __restrict__ bk,
                                                u16* __restrict__ qk) {
    __shared__ __align__(16) u16 At[128 * 64];
    __shared__ __align__(16) u16 Bt[128 * 64];
    int tid = threadIdx.x, l6 = tid & 63, w = tid >> 6;
    int m0 = blockIdx.x * 128;
    const f32x4 vzero = {0.f, 0.f, 0.f, 0.f};
    f32x4 acc[2][8];
    #pragma unroll
    for (int i = 0; i < 2; ++i)
        #pragma unroll
        for (int j = 0; j < 8; ++j) acc[i][j] = vzero;

    for (int kt = 0; kt < 16; ++kt) {
        __syncthreads();
        {   // stage A: x fp32 -> bf16 swizzled
            int r = tid >> 4, c4 = tid & 15;
            #pragma unroll
            for (int pass = 0; pass < 8; ++pass) {
                int rr = r + pass * 16;
                float4 v = *(const float4*)&x[(size_t)(m0 + rr) * HH + kt * 64 + c4 * 4];
                ushort4 h;
                h.x = f2b(v.x); h.y = f2b(v.y); h.z = f2b(v.z); h.w = f2b(v.w);
                *(ushort4*)&At[swze(rr, c4 * 4)] = h;
            }
            stage_bf16(Bt, &wt[kt * 64], HH, tid);
        }
        __syncthreads();
        bf16x8 af[2][2];
        #pragma unroll
        for (int i = 0; i < 2; ++i)
            #pragma unroll
            for (int ks = 0; ks < 2; ++ks) af[i][ks] = ldfrag(At, w * 32 + i * 16, ks, l6);
        #pragma unroll
        for (int j = 0; j < 8; ++j) {
            bf16x8 b0 = ldfrag(Bt, j * 16, 0, l6);
            bf16x8 b1 = ldfrag(Bt, j * 16, 1, l6);
            acc[0][j] = MFMA16(af[0][0], b0, acc[0][j], 0, 0, 0);
            acc[0][j] = MFMA16(af[0][1], b1, acc[0][j], 0, 0, 0);
            acc[1][j] = MFMA16(af[1][0], b0, acc[1][j], 0, 0, 0);
            acc[1][j] = MFMA16(af[1][1], b1, acc[1][j], 0, 0, 0);
        }
    }
    #pragma unroll
    for (int j = 0; j < 8; ++j) {
        int n = j * 16 + (l6 & 15);
        float bias = (n < 64) ? bq[n] : bk[n - 64];
        #pragma unroll
        for (int i = 0; i < 2; ++i) {
            int mrow = m0 + w * 32 + i * 16 + ((l6 >> 4) << 2);
            #pragma unroll
            for (int r4 = 0; r4 < 4; ++r4)
                qk[(size_t)(mrow + r4) * 128 + n] = f2b(acc[i][j][r4] + bias);
        }
    }
}

// ---- E: Nb per batch ----
__global__ __launch_bounds__(256) void k_nb(const int* __restrict__ mask,
                                            float* __restrict__ nbv) {
    int b = blockIdx.x, tid = threadIdx.x;
    int s = 0;
    for (int i = tid; i < SS; i += 256) s += mask[b * SS + i];
    float fs = (float)s;
    for (int off = 1; off < 64; off <<= 1) fs += __shfl_xor(fs, off);
    __shared__ float red[4];
    if ((tid & 63) == 0) red[tid >> 6] = fs;
    __syncthreads();
    if (tid == 0) nbv[b] = red[0] + red[1] + red[2] + red[3] + 1e-8f;
}

// ---- C: softmax denominators l[b][s]: block = 128 s rows x all 2048 t ----
__global__ __launch_bounds__(256) void k_rowsum(const u16* __restrict__ qk,
                                                const int* __restrict__ mask,
                                                float* __restrict__ l) {
    int b = blockIdx.x, sblk = blockIdx.y;
    __shared__ __align__(16) u16 Qs[128 * 64];
    __shared__ __align__(16) u16 Ks[128 * 64];
    __shared__ float pmsh[2048];
    int tid = threadIdx.x, l6 = tid & 63, w = tid >> 6;
    for (int i = tid; i < 2048; i += 256) pmsh[i] = mask[b * SS + i] ? 1.f : 0.f;
    stage_bf16(Qs, qk + (size_t)(b * SS + sblk * 128) * 128, 128, tid);
    __syncthreads();
    bf16x8 qf[2][2];
    #pragma unroll
    for (int i = 0; i < 2; ++i)
        #pragma unroll
        for (int ks = 0; ks < 2; ++ks) qf[i][ks] = ldfrag(Qs, w * 32 + i * 16, ks, l6);
    float rsum[2][4] = {};
    const f32x4 vzero = {0.f, 0.f, 0.f, 0.f};
    for (int tt = 0; tt < 16; ++tt) {
        __syncthreads();
        stage_bf16(Ks, qk + (size_t)(b * SS + tt * 128) * 128 + 64, 128, tid);
        __syncthreads();
        #pragma unroll
        for (int j = 0; j < 8; ++j) {
            bf16x8 k0 = ldfrag(Ks, j * 16, 0, l6);
            bf16x8 k1 = ldfrag(Ks, j * 16, 1, l6);
            f32x4 a0 = vzero, a1 = vzero;
            a0 = MFMA16(qf[0][0], k0, a0, 0, 0, 0);
            a0 = MFMA16(qf[0][1], k1, a0, 0, 0, 0);
            a1 = MFMA16(qf[1][0], k0, a1, 0, 0, 0);
            a1 = MFMA16(qf[1][1], k1, a1, 0, 0, 0);
            float pm = pmsh[tt * 128 + j * 16 + (l6 & 15)];
            #pragma unroll
            for (int r4 = 0; r4 < 4; ++r4) {
                rsum[0][r4] += pm * __expf(a0[r4] * 0.125f);
                rsum[1][r4] += pm * __expf(a1[r4] * 0.125f);
            }
        }
    }
    #pragma unroll
    for (int off = 1; off < 16; off <<= 1)
        #pragma unroll
        for (int i = 0; i < 2; ++i)
            #pragma unroll
            for (int r4 = 0; r4 < 4; ++r4) rsum[i][r4] += __shfl_xor(rsum[i][r4], off);
    if ((l6 & 15) == 0) {
        int base = b * SS + sblk * 128 + w * 32;
        #pragma unroll
        for (int i = 0; i < 2; ++i)
            #pragma unroll
            for (int r4 = 0; r4 < 4; ++r4)
                l[base + i * 16 + ((l6 >> 4) << 2) + r4] = rsum[i][r4];
    }
}

// ---- D: column sums: block = 128 t cols x all 2048 s; direct store ----
__global__ __launch_bounds__(256) void k_colsum(const u16* __restrict__ qk,
                                                const int* __restrict__ mask,
                                                const float* __restrict__ l,
                                                float* __restrict__ ca,
                                                float* __restrict__ cm) {
    int b = blockIdx.x, tg = blockIdx.y;
    __shared__ __align__(16) u16 Ks[128 * 64];
    __shared__ __align__(16) u16 Qs[128 * 64];
    __shared__ float invlsh[2048];
    __shared__ float qmlsh[2048];
    __shared__ float redbuf[4][2][128];
    int tid = threadIdx.x, l6 = tid & 63, w = tid >> 6;
    for (int i = tid; i < 2048; i += 256) {
        float lv = l[b * SS + i];
        float inv = (lv > 0.f) ? 1.f / lv : 0.f;
        invlsh[i] = inv;
        qmlsh[i] = mask[b * SS + i] ? inv : 0.f;
    }
    stage_bf16(Ks, qk + (size_t)(b * SS + tg * 128) * 128 + 64, 128, tid);
    float ca2[8] = {}, cm2[8] = {};
    const f32x4 vzero = {0.f, 0.f, 0.f, 0.f};
    for (int st = 0; st < 16; ++st) {
        __syncthreads();
        stage_bf16(Qs, qk + (size_t)(b * SS + st * 128) * 128, 128, tid);
        __syncthreads();
        bf16x8 qf[2][2];
        #pragma unroll
        for (int i = 0; i < 2; ++i)
            #pragma unroll
            for (int ks = 0; ks < 2; ++ks) qf[i][ks] = ldfrag(Qs, w * 32 + i * 16, ks, l6);
        float il[2][4], qml[2][4];
        int sbase = st * 128 + w * 32;
        #pragma unroll
        for (int i = 0; i < 2; ++i)
            #pragma unroll
            for (int r4 = 0; r4 < 4; ++r4) {
                int s = sbase + i * 16 + ((l6 >> 4) << 2) + r4;
                il[i][r4] = invlsh[s];
                qml[i][r4] = qmlsh[s];
            }
        #pragma unroll
        for (int j = 0; j < 8; ++j) {
            bf16x8 k0 = ldfrag(Ks, j * 16, 0, l6);
            bf16x8 k1 = ldfrag(Ks, j * 16, 1, l6);
            f32x4 a0 = vzero, a1 = vzero;
            a0 = MFMA16(qf[0][0], k0, a0, 0, 0, 0);
            a0 = MFMA16(qf[0][1], k1, a0, 0, 0, 0);
            a1 = MFMA16(qf[1][0], k0, a1, 0, 0, 0);
            a1 = MFMA16(qf[1][1], k1, a1, 0, 0, 0);
            float sca = 0.f, scm = 0.f;
            #pragma unroll
            for (int r4 = 0; r4 < 4; ++r4) {
                float e0 = __expf(a0[r4] * 0.125f);
                float e1 = __expf(a1[r4] * 0.125f);
                sca += e0 * il[0][r4] + e1 * il[1][r4];
                scm += e0 * qml[0][r4] + e1 * qml[1][r4];
            }
            ca2[j] += sca;
            cm2[j] += scm;
        }
    }
    #pragma unroll
    for (int off = 16; off < 64; off <<= 1)
        #pragma unroll
        for (int j = 0; j < 8; ++j) {
            ca2[j] += __shfl_xor(ca2[j], off);
            cm2[j] += __shfl_xor(cm2[j], off);
        }
    __syncthreads();
    if (l6 < 16)
        #pragma unroll
        for (int j = 0; j < 8; ++j) {
            redbuf[w][0][j * 16 + l6] = ca2[j];
            redbuf[w][1][j * 16 + l6] = cm2[j];
        }
    __syncthreads();
    {
        int bufi = tid >> 7, tl = tid & 127;
        float s = redbuf[0][bufi][tl] + redbuf[1][bufi][tl]
                + redbuf[2][bufi][tl] + redbuf[3][bufi][tl];
        float pm = mask[b * SS + tg * 128 + tl] ? 1.f : 0.f;
        if (bufi == 0) ca[b * SS + tg * 128 + tl] = s * pm;
        else           cm[b * SS + tg * 128 + tl] = s * pm;
    }
}

// ---- F: w, attn_mean, wsum ----
__global__ __launch_bounds__(256) void k_finalize(const float* __restrict__ ca,
                                                  const float* __restrict__ cmv,
                                                  const float* __restrict__ nbv,
                                                  float* __restrict__ w,
                                                  float* __restrict__ wsum,
                                                  float* __restrict__ out_mean) {
    int b = blockIdx.x;
    int t = blockIdx.y * 256 + threadIdx.x;
    float cav = ca[b * SS + t];
    out_mean[b * SS + t] = cav * (1.f / SS);
    float wv = cmv[b * SS + t] / nbv[b];
    w[b * SS + t] = wv;
    float s = wv;
    for (int off = 1; off < 64; off <<= 1) s += __shfl_xor(s, off);
    if ((threadIdx.x & 63) == 0) atomicAdd(&wsum[b], s);
}

// ---- G: u[b][c] = sum_t w[b][t] * x[b][t][c] ----
__global__ __launch_bounds__(256) void k_u(const float* __restrict__ x,
                                           const float* __restrict__ w,
                                           float* __restrict__ u) {
    int b = blockIdx.x;
    int c = blockIdx.y * 256 + threadIdx.x;
    int t0 = blockIdx.z * 256;
    const float* xb = &x[((size_t)b * SS + t0) * HH + c];
    const float* wb = &w[b * SS + t0];
    float acc = 0.f;
    #pragma unroll 8
    for (int t = 0; t < 256; ++t)
        acc += wb[t] * xb[(size_t)t * HH];
    atomicAdd(&u[b * HH + c], acc);
}

// ---- H: out0[b][h] = sum_c u[b][c]*Wv[c][h] + bv[h]*wsum[b] ----
__global__ __launch_bounds__(256) void k_out0(const float* __restrict__ u,
                                              const float* __restrict__ Wv,
                                              const float* __restrict__ bv,
                                              const float* __restrict__ wsum,
                                              float* __restrict__ out) {
    int b = blockIdx.x;
    int h = blockIdx.y * 256 + threadIdx.x;
    const float* ub = &u[b * HH];
    float acc = bv[h] * wsum[b];
    #pragma unroll 8
    for (int c = 0; c < HH; ++c)
        acc += ub[c] * Wv[(size_t)c * HH + h];
    out[b * HH + h] = acc;
}

extern "C" void kernel_launch(void* const* d_in, const int* in_sizes, int n_in,
                              void* d_out, int out_size, void* d_ws, size_t ws_size,
                              hipStream_t stream) {
    const float* x  = (const float*)d_in[0];
    const int* mask = (const int*)d_in[1];
    const float* Wq = (const float*)d_in[2];
    const float* bq = (const float*)d_in[3];
    const float* Wk = (const float*)d_in[4];
    const float* bk = (const float*)d_in[5];
    const float* Wv = (const float*)d_in[6];
    const float* bv = (const float*)d_in[7];
    float* out = (float*)d_out;
    float* ws  = (float*)d_ws;

    u16*   qk   = (u16*)(ws + QK_OFF);
    u16*   wt   = (u16*)(ws + WT_OFF);
    float* l    = ws + L_OFF;
    float* ca   = ws + CA_OFF;
    float* cm   = ws + CM_OFF;
    float* w    = ws + W_OFF;
    float* nbv  = ws + NB_OFF;
    float* wsum = ws + WSUM_OFF;
    float* u    = ws + U_OFF;

    // only wsum + u are accumulated via atomics; everything else is stored directly
    hipMemsetAsync(wsum, 0, (size_t)(16 + BN_ * HH) * sizeof(float), stream);

    k_wt     <<<dim3(128),      dim3(256), 0, stream>>>(Wq, Wk, wt);
    k_qkproj <<<dim3(256),      dim3(256), 0, stream>>>(x, wt, bq, bk, qk);
    k_nb     <<<dim3(BN_),      dim3(256), 0, stream>>>(mask, nbv);
    k_rowsum <<<dim3(BN_, 16),  dim3(256), 0, stream>>>(qk, mask, l);
    k_colsum <<<dim3(BN_, 16),  dim3(256), 0, stream>>>(qk, mask, l, ca, cm);
    k_finalize<<<dim3(BN_, 8),  dim3(256), 0, stream>>>(ca, cm, nbv, w, wsum, out + BN_ * HH);
    k_u      <<<dim3(BN_, 4, 8), dim3(256), 0, stream>>>(x, w, u);
    k_out0   <<<dim3(BN_, 4),   dim3(256), 0, stream>>>(u, Wv, bv, wsum, out);
}